// Round 14
// baseline (427.902 us; speedup 1.0000x reference)
//
#include <hip/hip_runtime.h>

#define FMAX 1024
#define NC 16       // channels
#define NB 16       // batch
#define HW (512 * 512)

constexpr int SEGS = 32;             // segments per image (sums blocks/image)
constexpr int SEG  = HW / SEGS;      // 8192 px per block
constexpr int TP   = 1024;           // pixels per tile
constexpr int NT   = SEG / TP;       // 8 tiles per block
constexpr int T    = 512;            // threads per block
constexpr int CHH  = 16;             // hist chunks per image

// workspace layout:
//   psums : (NB*SEGS=512) slabs of [FMAX][16] f32 = 32 MiB
//   phist : (NB*CHH=256) slabs of [FMAX][16] i32  = 16 MiB
//   tot_n : 2 floats

__device__ __forceinline__ unsigned short f2bf(float x) {
    const unsigned u = __float_as_uint(x);
    return (unsigned short)((u + 0x7FFFu + ((u >> 16) & 1u)) >> 16);  // RN bf16
}

// ---------------------------------------------------------------------------
// Kernel 1: bucket-sort segment-sum. Per tile of 1024 px: stage logits to LDS
// (bf16, ch-major), count fields (LDS atomics on pixel IDs only), wave-shuffle
// prefix scan, place ids, then GATHER per-field (divergent ds_read_u16 at bank
// throughput, no atomics). Each thread owns fields {tid, tid+512}, f32 regs.
// ---------------------------------------------------------------------------
__global__ __launch_bounds__(T) void sums_kernel(
    const float* __restrict__ logits,   // (B, C, HW)
    const int* __restrict__ fids,       // (B, HW)
    float* __restrict__ psums)          // 512 slabs x [FMAX][NC] f32
{
    __shared__ unsigned short lg[NC][TP];   // 32 KB bf16 tile, ch-major
    __shared__ int cnt[FMAX];               // 4 KB per-tile field counts
    __shared__ int baseA[FMAX];             // 4 KB mutable base (place)
    __shared__ int baseB[FMAX];             // 4 KB read base (gather)
    __shared__ unsigned short ids[TP];      // 2 KB bucketed local px ids
    __shared__ int wtot[8];                 // per-wave scan totals

    const int b   = blockIdx.x / SEGS;
    const int sg  = blockIdx.x % SEGS;
    const int p0  = sg * SEG;
    const int tid = threadIdx.x;
    const int lane = tid & 63;
    const int wv   = tid >> 6;

    float acc[2][NC];
    #pragma unroll
    for (int fi = 0; fi < 2; ++fi)
        #pragma unroll
        for (int c = 0; c < NC; ++c) acc[fi][c] = 0.0f;

    const float* lgp = logits + (size_t)b * NC * HW + p0;
    const int*   fb  = fids   + (size_t)b * HW + p0;

    for (int t = 0; t < NT; ++t) {
        const int tp0 = t * TP;

        // ---- stage tile: 16 ch x 1024 px -> bf16 LDS (ch-major) ----
        #pragma unroll
        for (int k = 0; k < 8; ++k) {
            const int task = tid + k * T;       // 0..4095 quad tasks
            const int c = task >> 8;            // 256 quads per channel
            const int q = task & 255;
            const float4 v = *reinterpret_cast<const float4*>(lgp + (size_t)c * HW + tp0 + q * 4);
            ushort4 h;
            h.x = f2bf(v.x); h.y = f2bf(v.y); h.z = f2bf(v.z); h.w = f2bf(v.w);
            *reinterpret_cast<ushort4*>(&lg[c][q * 4]) = h;
        }
        cnt[tid] = 0; cnt[tid + 512] = 0;
        __syncthreads();

        // ---- count (2 px per thread, coalesced fid reads) ----
        const int f0 = fb[tp0 + tid];
        const int f1 = fb[tp0 + tid + 512];
        atomicAdd(&cnt[f0], 1);
        atomicAdd(&cnt[f1], 1);
        __syncthreads();

        // ---- exclusive prefix scan of cnt[1024] (pair + wave shuffle) ----
        const int e0 = cnt[2 * tid];
        const int e1 = cnt[2 * tid + 1];
        const int s2 = e0 + e1;
        int incl = s2;
        #pragma unroll
        for (int d = 1; d < 64; d <<= 1) {
            const int g = __shfl_up(incl, d, 64);
            if (lane >= d) incl += g;
        }
        if (lane == 63) wtot[wv] = incl;
        __syncthreads();
        int wbase = 0;
        #pragma unroll
        for (int w = 0; w < 8; ++w) if (w < wv) wbase += wtot[w];
        const int pairbase = wbase + incl - s2;     // exclusive base of elem 2*tid
        baseA[2 * tid]     = pairbase;
        baseA[2 * tid + 1] = pairbase + e0;
        baseB[2 * tid]     = pairbase;
        baseB[2 * tid + 1] = pairbase + e0;
        __syncthreads();

        // ---- place pixel ids into buckets ----
        const int s0 = atomicAdd(&baseA[f0], 1);
        ids[s0] = (unsigned short)tid;
        const int s1 = atomicAdd(&baseA[f1], 1);
        ids[s1] = (unsigned short)(tid + 512);
        __syncthreads();

        // ---- gather: thread owns fields tid, tid+512 ----
        #pragma unroll
        for (int fi = 0; fi < 2; ++fi) {
            const int f = tid + fi * 512;
            const int n = cnt[f];
            const int base = baseB[f];
            for (int j = 0; j < n; ++j) {
                const int id = ids[base + j];
                #pragma unroll
                for (int c = 0; c < NC; ++c)
                    acc[fi][c] += __uint_as_float(((unsigned)lg[c][id]) << 16);
            }
        }
        __syncthreads();    // protect lg/cnt/ids before next tile
    }

    // ---- epilogue: write slab rows (f-major, 64B/row, coalesced) ----
    float* out = psums + (size_t)blockIdx.x * (FMAX * NC);
    #pragma unroll
    for (int fi = 0; fi < 2; ++fi) {
        float* row = out + (size_t)(tid + fi * 512) * NC;
        #pragma unroll
        for (int k = 0; k < 4; ++k)
            reinterpret_cast<float4*>(row)[k] = make_float4(
                acc[fi][4 * k], acc[fi][4 * k + 1], acc[fi][4 * k + 2], acc[fi][4 * k + 3]);
    }
}

// ---------------------------------------------------------------------------
// Kernel 2: per-(image,chunk) (field,label) histogram, LDS-staged
// ---------------------------------------------------------------------------
__global__ __launch_bounds__(T) void hist_kernel(
    const int* __restrict__ masks,      // (B, HW)
    const int* __restrict__ fids,       // (B, HW)
    int* __restrict__ phist)            // (B*CHH) x [FMAX][16]
{
    __shared__ int lh[NC * FMAX];       // 64 KB, [lab][f]

    const int b  = blockIdx.x / CHH;
    const int ch = blockIdx.x % CHH;
    constexpr int PPB = HW / CHH;       // 16384
    const int p0 = ch * PPB;

    for (int i = threadIdx.x; i < NC * FMAX; i += T) lh[i] = 0;
    __syncthreads();

    const int* fb = fids  + (size_t)b * HW + p0;
    const int* lb = masks + (size_t)b * HW + p0;

    constexpr int PASSES = PPB / (T * 4);   // 8
    #pragma unroll
    for (int pass = 0; pass < PASSES; ++pass) {
        const int i4 = (pass * T + threadIdx.x) * 4;
        const int4 f4 = *reinterpret_cast<const int4*>(fb + i4);
        const int4 l4 = *reinterpret_cast<const int4*>(lb + i4);
        atomicAdd(&lh[l4.x * FMAX + f4.x], 1);
        atomicAdd(&lh[l4.y * FMAX + f4.y], 1);
        atomicAdd(&lh[l4.z * FMAX + f4.z], 1);
        atomicAdd(&lh[l4.w * FMAX + f4.w], 1);
    }
    __syncthreads();

    // dump transposed: slab row f holds 16 consecutive label counts (64B)
    int* out = phist + (size_t)blockIdx.x * (FMAX * NC);
    for (int j = threadIdx.x; j < FMAX * NC / 4; j += T) {
        const int f  = j >> 2;
        const int c0 = (j & 3) * 4;
        int4 v;
        v.x = lh[(c0 + 0) * FMAX + f];
        v.y = lh[(c0 + 1) * FMAX + f];
        v.z = lh[(c0 + 2) * FMAX + f];
        v.w = lh[(c0 + 3) * FMAX + f];
        reinterpret_cast<int4*>(out)[j] = v;
    }
}

// ---------------------------------------------------------------------------
// Kernel 3: reduce partials (coalesced), per-(b,field) CE vs mode label
// ---------------------------------------------------------------------------
__global__ __launch_bounds__(256) void finalize_kernel(
    const float* __restrict__ psums,
    const int* __restrict__ phist,
    float* __restrict__ tot_n)          // [0]=total ce, [1]=count
{
    const int idx = blockIdx.x * 256 + threadIdx.x;   // b*FMAX + f
    const int b = idx >> 10;
    const int f = idx & (FMAX - 1);

    float sv[NC];
    int   hv[NC];
    #pragma unroll
    for (int c = 0; c < NC; ++c) { sv[c] = 0.0f; hv[c] = 0; }

    // psums: slab (b*SEGS+s), row f = 16 contiguous f32 (4 x float4)
    for (int s = 0; s < SEGS; ++s) {
        const float* p = psums + ((size_t)(b * SEGS + s)) * (FMAX * NC) + (size_t)f * NC;
        #pragma unroll
        for (int k = 0; k < 4; ++k) {
            const float4 v = reinterpret_cast<const float4*>(p)[k];
            sv[k * 4 + 0] += v.x; sv[k * 4 + 1] += v.y;
            sv[k * 4 + 2] += v.z; sv[k * 4 + 3] += v.w;
        }
    }
    // phist: slab (b*CHH+ch), row f = 16 contiguous ints (4 x int4)
    for (int ch = 0; ch < CHH; ++ch) {
        const int* p = phist + ((size_t)(b * CHH + ch)) * (FMAX * NC) + (size_t)f * NC;
        #pragma unroll
        for (int k = 0; k < 4; ++k) {
            const int4 v = reinterpret_cast<const int4*>(p)[k];
            hv[k * 4 + 0] += v.x; hv[k * 4 + 1] += v.y;
            hv[k * 4 + 2] += v.z; hv[k * 4 + 3] += v.w;
        }
    }

    int cnt = 0;
    #pragma unroll
    for (int c = 0; c < NC; ++c) cnt += hv[c];

    float ce = 0.0f;
    float w  = 0.0f;
    if (f != 0 && cnt > 0) {
        int ma = 0;
        #pragma unroll
        for (int c = 1; c < NC; ++c) if (hv[c] > hv[ma]) ma = c;
        int mv = 1;
        #pragma unroll
        for (int c = 2; c < NC; ++c) if (hv[c] > hv[mv]) mv = c;
        int vcnt = 0;
        #pragma unroll
        for (int c = 1; c < NC; ++c) vcnt += hv[c];
        const int label = (vcnt > 0) ? mv : ma;

        const float inv = 1.0f / (float)cnt;
        float mean[NC];
        float m = -1e30f;
        #pragma unroll
        for (int c = 0; c < NC; ++c) {
            mean[c] = sv[c] * inv;
            m = fmaxf(m, mean[c]);
        }
        float se = 0.0f;
        #pragma unroll
        for (int c = 0; c < NC; ++c) se += expf(mean[c] - m);
        const float logz = m + logf(se);

        float picked = 0.0f;
        #pragma unroll
        for (int c = 0; c < NC; ++c) picked = (c == label) ? mean[c] : picked;

        ce = logz - picked;
        w  = 1.0f;
    }

    #pragma unroll
    for (int off = 32; off > 0; off >>= 1) {
        ce += __shfl_down(ce, off, 64);
        w  += __shfl_down(w,  off, 64);
    }
    __shared__ float rce[4], rw[4];
    const int wid  = threadIdx.x >> 6;
    const int lane = threadIdx.x & 63;
    if (lane == 0) { rce[wid] = ce; rw[wid] = w; }
    __syncthreads();
    if (threadIdx.x == 0) {
        atomicAdd(&tot_n[0], rce[0] + rce[1] + rce[2] + rce[3]);
        atomicAdd(&tot_n[1], rw[0] + rw[1] + rw[2] + rw[3]);
    }
}

// ---------------------------------------------------------------------------
// Kernel 4: final scalar
// ---------------------------------------------------------------------------
__global__ void out_kernel(const float* __restrict__ tot_n, float* __restrict__ out)
{
    const float n = tot_n[1];
    out[0] = (n > 0.0f) ? (tot_n[0] / n) : 0.0f;
}

// ---------------------------------------------------------------------------
extern "C" void kernel_launch(void* const* d_in, const int* in_sizes, int n_in,
                              void* d_out, int out_size, void* d_ws, size_t ws_size,
                              hipStream_t stream)
{
    const float* logits = (const float*)d_in[0];
    const int*   masks  = (const int*)d_in[1];
    const int*   fids   = (const int*)d_in[2];

    const size_t psums_bytes = (size_t)NB * SEGS * FMAX * NC * sizeof(float); // 32 MiB
    const size_t phist_bytes = (size_t)NB * CHH * FMAX * NC * sizeof(int);    // 16 MiB
    float* psums = (float*)d_ws;
    int*   phist = (int*)((char*)d_ws + psums_bytes);
    float* tot_n = (float*)((char*)d_ws + psums_bytes + phist_bytes);

    hipMemsetAsync(tot_n, 0, 2 * sizeof(float), stream);

    hist_kernel<<<NB * CHH, T, 0, stream>>>(masks, fids, phist);
    sums_kernel<<<NB * SEGS, T, 0, stream>>>(logits, fids, psums);
    finalize_kernel<<<NB * FMAX / 256, 256, 0, stream>>>(psums, phist, tot_n);
    out_kernel<<<1, 1, 0, stream>>>(tot_n, (float*)d_out);
}